// Round 11
// baseline (272.002 us; speedup 1.0000x reference)
//
#include <hip/hip_runtime.h>
#include <hip/hip_bf16.h>

typedef __attribute__((ext_vector_type(8))) short short8;
typedef __attribute__((ext_vector_type(4))) float f32x4;

#define NNODES 50000

__device__ __forceinline__ float b2f(unsigned short s) {
  union { unsigned int u; float f; } c; c.u = ((unsigned int)s) << 16;
  return c.f;
}
__device__ __forceinline__ unsigned short f2b(float f) {
  return __bfloat16_as_ushort(__float2bfloat16(f));  // RNE
}
__device__ __forceinline__ unsigned int pkcvt(float a, float b) {
  return (unsigned int)f2b(a) | ((unsigned int)f2b(b) << 16);
}

// global_load_lds, 16B per lane: per-lane GLOBAL src addr, wave-uniform LDS
// base; HW writes LDS at base + lane*16 (m104 semantics).
__device__ __forceinline__ void gl_lds16(const void* g, void* l) {
  __builtin_amdgcn_global_load_lds((const __attribute__((address_space(1))) unsigned int*)g,
                                   (__attribute__((address_space(3))) unsigned int*)l, 16, 0, 0);
}

// ---------------- degree histogram (+rank capture) + W transpose/bf16 ----------------
__global__ __launch_bounds__(256) void k_deg(const int* __restrict__ ei, int* __restrict__ deg, int E,
                                             int* __restrict__ rnk,
                                             const float* __restrict__ W1, const float* __restrict__ W2,
                                             unsigned short* __restrict__ w1t, unsigned short* __restrict__ w2t) {
  int idx = blockIdx.x * 256 + threadIdx.x;
  if (idx < E) {
    int r = atomicAdd(&deg[ei[E + idx]], 1);
    rnk[idx] = r;
  }
  if (idx < 256 * 512) { int nn = idx >> 9, kk = idx & 511; w1t[idx] = f2b(W1[kk * 256 + nn]); }
  int i2 = idx - 256 * 512;
  if (i2 >= 0 && i2 < 64 * 256) { int nn = i2 >> 8, kk = i2 & 255; w2t[i2] = f2b(W2[kk * 64 + nn]); }
}

// ---------------- scan phase A ----------------
__global__ __launch_bounds__(256) void k_scanA(const int* __restrict__ deg, int* __restrict__ excl,
                                               int* __restrict__ blksum, float* __restrict__ dinv, int n) {
  const int i = blockIdx.x * 256 + threadIdx.x;
  const int lane = threadIdx.x & 63, wid = threadIdx.x >> 6;
  const int v = (i < n) ? deg[i] : 0;
  int x = v;
#pragma unroll
  for (int o = 1; o < 64; o <<= 1) {
    int y = __shfl_up(x, o, 64);
    if (lane >= o) x += y;
  }
  __shared__ int wsum[4];
  if (lane == 63) wsum[wid] = x;
  __syncthreads();
  int woff = 0;
  for (int w = 0; w < wid; ++w) woff += wsum[w];
  const int incl = x + woff;
  if (i < n) {
    excl[i] = incl - v;
    dinv[i] = rsqrtf((float)v + 1.0f);  // +1 self loop
  }
  if (threadIdx.x == 255) blksum[blockIdx.x] = incl;
}

// ---------------- scan phase C ----------------
__global__ __launch_bounds__(256) void k_scanC(const int* __restrict__ excl, const int* __restrict__ blksum,
                                               int* __restrict__ rowptr, int n, int E) {
  const int t = threadIdx.x;
  int partial = 0;
  for (int j = t; j < (int)blockIdx.x; j += 256) partial += blksum[j];
#pragma unroll
  for (int o = 32; o > 0; o >>= 1) partial += __shfl_xor(partial, o, 64);
  __shared__ int ws[4];
  if ((t & 63) == 0) ws[t >> 6] = partial;
  __syncthreads();
  const int off = ws[0] + ws[1] + ws[2] + ws[3];
  const int i = blockIdx.x * 256 + t;
  if (i < n) rowptr[i] = excl[i] + off;
  if (i == 0) rowptr[n] = E;
}

// ---------------- atomic-free CSR fill + x->bf16 conversion (fused) ----------------
__global__ __launch_bounds__(256) void k_fillx(const int* __restrict__ ei, const int* __restrict__ rowptr,
                                               const int* __restrict__ rnk, int* __restrict__ csr, int E,
                                               const float* __restrict__ x, unsigned short* __restrict__ xb) {
  int idx = blockIdx.x * 256 + threadIdx.x;
  if (idx < E) {
    const int dst = ei[E + idx];
    csr[rowptr[dst] + rnk[idx]] = ei[idx];
  }
  if (idx < (NNODES * 512) / 8) {
    const float4 v0 = *(const float4*)(x + (size_t)idx * 8);
    const float4 v1 = *(const float4*)(x + (size_t)idx * 8 + 4);
    uint4 p;
    p.x = pkcvt(v0.x, v0.y); p.y = pkcvt(v0.z, v0.w);
    p.z = pkcvt(v1.x, v1.y); p.w = pkcvt(v1.z, v1.w);
    *(uint4*)(xb + (size_t)idx * 8) = p;
  }
}

// ---------------- GEMM1: hs1cb = bf16(dinv[row] * (xb @ W1)), 32-col-blocked ----------------
// R7 config (128x64, measured local optimum). Depth-2 pipelined gl_lds
// staging, counted vmcnt(3), both-sides chunk-XOR swizzle. Output layout
// hs1cb[8][node][32]: each 32-col slab is 3.2MB -> FITS the 4MiB per-XCD L2
// (R10's 12.8MB half-slab did not: hit rate only 61%, fetch 158.8MB).
__global__ __launch_bounds__(256) void k_gemm1(const unsigned short* __restrict__ xb,
    const unsigned short* __restrict__ w1t, const float* __restrict__ dinv,
    unsigned short* __restrict__ hs1cb) {
  const int M = NNODES, K = 512;
  const int NRB = (NNODES + 127) / 128;  // 391
  const int bid = blockIdx.x;
  const int rowblk = (bid >> 5) * 8 + (bid & 7);
  const int colblk = (bid >> 3) & 3;
  if (rowblk >= NRB) return;

  __shared__ unsigned short Ab[2][128][32];  // 16 KB
  __shared__ unsigned short Bb[2][64][32];   //  8 KB

  const int tid = threadIdx.x;
  const int w = tid >> 6, lane = tid & 63;
  const int sub = lane >> 2;                 // staging row within wave window
  const int brow = rowblk * 128, bcol = colblk * 64;
  const int wr = w >> 1, wc = w & 1;         // 2x2 wave grid, 64x32 out each
  const int lr = lane & 15, lk = lane >> 4;

  const int swc = ((lane & 3) ^ ((lane >> 3) & 3)) * 8;   // pre-swizzled src chunk
  const int rch = (lk ^ ((lr >> 1) & 3)) * 8;             // read-side swizzled chunk

  int gr0 = brow + w * 16 + sub;      if (gr0 >= M) gr0 = M - 1;
  int gr1 = brow + 64 + w * 16 + sub; if (gr1 >= M) gr1 = M - 1;
  const int grB = bcol + w * 16 + sub;

  const unsigned short* a0p = xb + (size_t)gr0 * K + swc;
  const unsigned short* a1p = xb + (size_t)gr1 * K + swc;
  const unsigned short* bp  = w1t + (size_t)grB * K + swc;

  f32x4 acc[4][2] = {};

#define G1_STAGE(BUF, KT) do { \
    gl_lds16(a0p + (KT), &Ab[BUF][w * 16][0]); \
    gl_lds16(a1p + (KT), &Ab[BUF][64 + w * 16][0]); \
    gl_lds16(bp  + (KT), &Bb[BUF][w * 16][0]); \
  } while (0)

  G1_STAGE(0, 0);
  G1_STAGE(1, 32);
  asm volatile("s_waitcnt vmcnt(3)" ::: "memory");  // stage 0 done; stage 1 in flight
  __builtin_amdgcn_s_barrier();

  for (int s = 0; s < 16; ++s) {
    const int cur = s & 1;
    short8 af[4], bf[2];
#pragma unroll
    for (int m = 0; m < 4; ++m) af[m] = *(const short8*)&Ab[cur][wr * 64 + m * 16 + lr][rch];
#pragma unroll
    for (int n = 0; n < 2; ++n) bf[n] = *(const short8*)&Bb[cur][wc * 32 + n * 16 + lr][rch];
    if (s < 14) {
      asm volatile("s_waitcnt lgkmcnt(0)" ::: "memory");  // frags in regs
      __builtin_amdgcn_s_barrier();                       // all waves done with buf cur
      G1_STAGE(cur, (s + 2) * 32);                        // tile s+2 -> buf cur
    }
#pragma unroll
    for (int m = 0; m < 4; ++m)
#pragma unroll
      for (int n = 0; n < 2; ++n)
        acc[m][n] = __builtin_amdgcn_mfma_f32_16x16x32_bf16(af[m], bf[n], acc[m][n], 0, 0, 0);
    if (s < 14)      asm volatile("s_waitcnt vmcnt(3)" ::: "memory");  // s+1 landed; s+2 in flight
    else if (s == 14) asm volatile("s_waitcnt vmcnt(0)" ::: "memory"); // last stage (tile 15) landed
    if (s < 15) __builtin_amdgcn_s_barrier();
  }
#undef G1_STAGE

#pragma unroll
  for (int m = 0; m < 4; ++m) {
#pragma unroll
    for (int n = 0; n < 2; ++n) {
      const int col = bcol + wc * 32 + n * 16 + lr;          // 0..255
      unsigned short* dst = hs1cb + (size_t)(col >> 5) * ((size_t)NNODES * 32);
      const int cw = col & 31;
#pragma unroll
      for (int j = 0; j < 4; ++j) {
        const int row = brow + wr * 64 + m * 16 + lk * 4 + j;
        if (row < M) dst[(size_t)row * 32 + cw] = f2b(acc[m][n][j] * dinv[row]);
      }
    }
  }
}

// ---------------- agg1: 8-pass L2-resident slab gather + relu/bias -> h1agg [8][n][32] ----------------
// pass = bid&7 -> XCD pinned (round-robin); each XCD gathers ONE 3.2MB slab
// that FITS its 4MiB L2 (R3 measured 46MB total fetch for this slab size).
// Wave layout fixes R3's failure mode: ONE dst per wave (no divergence),
// 4 edge-groups x 16 lanes (64B slice = 16 x ushort2), groups take edges
// e+g stride 4 -> unconditional 4-deep batches (16 edges in flight); same
// wave-instruction count per edge as R10, quarter the bytes. Cross-group
// combine: 2 shfl_xor. Wave processes 4 dsts sequentially.
__global__ __launch_bounds__(256) void k_agg1(const int* __restrict__ rowptr,
    const int* __restrict__ csr, const unsigned short* __restrict__ hs1cb,
    const float* __restrict__ dinv, const float* __restrict__ b1,
    unsigned short* __restrict__ h1agg) {
  const int pass = blockIdx.x & 7;
  const int chunk = blockIdx.x >> 3;
  const int w = threadIdx.x >> 6, lane = threadIdx.x & 63;
  const int g = lane >> 4;        // edge group 0..3
  const int cl = lane & 15;       // column lane: cols cl*2, cl*2+1
  const size_t SL = (size_t)NNODES * 32;
  const unsigned short* __restrict__ src = hs1cb + (size_t)pass * SL;
  const float2 bb = *(const float2*)(b1 + pass * 32 + cl * 2);

  for (int i = 0; i < 4; ++i) {
    const int d = chunk * 16 + w * 4 + i;
    if (d >= NNODES) return;  // d monotonic in i; wave-uniform exit
    const int a = rowptr[d], bnd = rowptr[d + 1];
    float a0 = 0.f, a1 = 0.f;
    if (g == 0) {  // self loop counted once
      unsigned int sv = *(const unsigned int*)(src + (size_t)d * 32 + cl * 2);
      a0 = b2f((unsigned short)(sv & 0xffff));
      a1 = b2f((unsigned short)(sv >> 16));
    }
    int e = a;
    for (; e + 16 <= bnd; e += 16) {       // 4 edges per group in flight
      int s[4];
#pragma unroll
      for (int j = 0; j < 4; ++j) s[j] = csr[e + g + 4 * j];
      unsigned int v[4];
#pragma unroll
      for (int j = 0; j < 4; ++j) v[j] = *(const unsigned int*)(src + (size_t)s[j] * 32 + cl * 2);
#pragma unroll
      for (int j = 0; j < 4; ++j) {
        a0 += b2f((unsigned short)(v[j] & 0xffff));
        a1 += b2f((unsigned short)(v[j] >> 16));
      }
    }
    for (; e + 4 <= bnd; e += 4) {         // 1 edge per group
      int s0 = csr[e + g];
      unsigned int v = *(const unsigned int*)(src + (size_t)s0 * 32 + cl * 2);
      a0 += b2f((unsigned short)(v & 0xffff));
      a1 += b2f((unsigned short)(v >> 16));
    }
    if (e + g < bnd) {                     // tail (0..3 edges)
      int s0 = csr[e + g];
      unsigned int v = *(const unsigned int*)(src + (size_t)s0 * 32 + cl * 2);
      a0 += b2f((unsigned short)(v & 0xffff));
      a1 += b2f((unsigned short)(v >> 16));
    }
    // combine the 4 edge-groups (lanes cl, cl+16, cl+32, cl+48)
    a0 += __shfl_xor(a0, 16, 64); a0 += __shfl_xor(a0, 32, 64);
    a1 += __shfl_xor(a1, 16, 64); a1 += __shfl_xor(a1, 32, 64);

    const float di = dinv[d];
    const float r0 = fmaxf(0.f, a0 * di + bb.x);
    const float r1 = fmaxf(0.f, a1 * di + bb.y);
    if (g == 0)
      *(unsigned int*)(h1agg + (size_t)pass * SL + (size_t)d * 32 + cl * 2) = pkcvt(r0, r1);
  }
}

// ---------------- GEMM2: hs2b = bf16(dinv[row] * (h1agg @ W2)) ----------------
// M=50000, N=64, K=256. A is slab-blocked h1agg[8][n][32]: k-step s reads
// slab s, a contiguous 64B run per row. Tile 64x64, 4 waves 2x2 (32x32 out),
// BK=32, 8 k-steps, depth-2 pipelined gl_lds, counted vmcnt(2), chunk-XOR
// swizzle. 782 blocks.
__global__ __launch_bounds__(256) void k_gemm2(const unsigned short* __restrict__ h1agg,
    const unsigned short* __restrict__ w2t, const float* __restrict__ dinv,
    unsigned short* __restrict__ hs2b) {
  const int M = NNODES;
  const size_t SL = (size_t)NNODES * 32;
  const int brow = blockIdx.x * 64;

  __shared__ unsigned short As[2][64][32];  // 4 KB x2
  __shared__ unsigned short Bs[2][64][32];  // 4 KB x2

  const int tid = threadIdx.x;
  const int w = tid >> 6, lane = tid & 63;
  const int sub = lane >> 2;
  const int wr = w >> 1, wc = w & 1;
  const int lr = lane & 15, lk = lane >> 4;

  const int swc = ((lane & 3) ^ ((lane >> 3) & 3)) * 8;   // pre-swizzled src chunk
  const int rch = (lk ^ ((lr >> 1) & 3)) * 8;             // read-side swizzled chunk

  int gr = brow + w * 16 + sub; if (gr >= M) gr = M - 1;
  const unsigned short* ap = h1agg + (size_t)gr * 32 + swc;             // + s*SL per step
  const unsigned short* bp = w2t + (size_t)(w * 16 + sub) * 256 + swc;  // + s*32 per step

  f32x4 acc[2][2] = {};

#define G2_STAGE(BUF, S) do { \
    gl_lds16(ap + (size_t)(S) * SL, &As[BUF][w * 16][0]); \
    gl_lds16(bp + (S) * 32,         &Bs[BUF][w * 16][0]); \
  } while (0)

  G2_STAGE(0, 0);
  G2_STAGE(1, 1);
  asm volatile("s_waitcnt vmcnt(2)" ::: "memory");  // stage 0 done; stage 1 in flight
  __builtin_amdgcn_s_barrier();

  for (int s = 0; s < 8; ++s) {
    const int cur = s & 1;
    short8 af[2], bf[2];
#pragma unroll
    for (int m = 0; m < 2; ++m) af[m] = *(const short8*)&As[cur][wr * 32 + m * 16 + lr][rch];
#pragma unroll
    for (int n = 0; n < 2; ++n) bf[n] = *(const short8*)&Bs[cur][wc * 32 + n * 16 + lr][rch];
    if (s < 6) {
      asm volatile("s_waitcnt lgkmcnt(0)" ::: "memory");
      __builtin_amdgcn_s_barrier();
      G2_STAGE(cur, s + 2);
    }
#pragma unroll
    for (int m = 0; m < 2; ++m)
#pragma unroll
      for (int n = 0; n < 2; ++n)
        acc[m][n] = __builtin_amdgcn_mfma_f32_16x16x32_bf16(af[m], bf[n], acc[m][n], 0, 0, 0);
    if (s < 6)      asm volatile("s_waitcnt vmcnt(2)" ::: "memory");
    else if (s == 6) asm volatile("s_waitcnt vmcnt(0)" ::: "memory");
    if (s < 7) __builtin_amdgcn_s_barrier();
  }
#undef G2_STAGE

#pragma unroll
  for (int m = 0; m < 2; ++m) {
#pragma unroll
    for (int n = 0; n < 2; ++n) {
      const int col = wc * 32 + n * 16 + lr;
#pragma unroll
      for (int j = 0; j < 4; ++j) {
        const int row = brow + wr * 32 + m * 16 + lk * 4 + j;
        if (row < M) hs2b[(size_t)row * 64 + col] = f2b(acc[m][n][j] * dinv[row]);
      }
    }
  }
}

// ---------------- fused agg2 + bias + log_softmax: wave per dst node (R7 version) ----------------
__global__ __launch_bounds__(256) void k_agg2f(const int* __restrict__ rowptr,
    const int* __restrict__ csr, const unsigned short* __restrict__ hs2b,
    const float* __restrict__ dinv, const float* __restrict__ b2,
    float* __restrict__ out) {
  const int d = blockIdx.x * 4 + (threadIdx.x >> 6);
  if (d >= NNODES) return;
  const int lane = threadIdx.x & 63;
  const int a = rowptr[d], bnd = rowptr[d + 1];

  float acc = b2f(hs2b[(size_t)d * 64 + lane]);

  int i = a;
  for (; i + 16 <= bnd; i += 16) {
    int s[16];
#pragma unroll
    for (int j = 0; j < 16; ++j) s[j] = csr[i + j];
    unsigned short v[16];
#pragma unroll
    for (int j = 0; j < 16; ++j) v[j] = hs2b[(size_t)s[j] * 64 + lane];
#pragma unroll
    for (int j = 0; j < 16; ++j) acc += b2f(v[j]);
  }
  for (; i + 4 <= bnd; i += 4) {
    int s[4];
#pragma unroll
    for (int j = 0; j < 4; ++j) s[j] = csr[i + j];
    unsigned short v[4];
#pragma unroll
    for (int j = 0; j < 4; ++j) v[j] = hs2b[(size_t)s[j] * 64 + lane];
#pragma unroll
    for (int j = 0; j < 4; ++j) acc += b2f(v[j]);
  }
  for (; i < bnd; ++i) acc += b2f(hs2b[(size_t)csr[i] * 64 + lane]);

  float v = acc * dinv[d] + b2[lane];
  float m = v;
#pragma unroll
  for (int o = 32; o > 0; o >>= 1) m = fmaxf(m, __shfl_xor(m, o, 64));
  float ex = expf(v - m);
  float s = ex;
#pragma unroll
  for (int o = 32; o > 0; o >>= 1) s += __shfl_xor(s, o, 64);
  out[(size_t)d * 64 + lane] = v - m - logf(s);
}

extern "C" void kernel_launch(void* const* d_in, const int* in_sizes, int n_in,
                              void* d_out, int out_size, void* d_ws, size_t ws_size,
                              hipStream_t stream) {
  const float* x  = (const float*)d_in[0];
  const int*   ei = (const int*)d_in[1];
  const float* W1 = (const float*)d_in[2];
  const float* b1 = (const float*)d_in[3];
  const float* W2 = (const float*)d_in[4];
  const float* b2 = (const float*)d_in[5];
  float* out = (float*)d_out;
  const int E = in_sizes[1] / 2;
  const int n = NNODES;
  const int nblk = (n + 255) / 256;

  char* ws = (char*)d_ws;
  size_t off = 0;
  auto alloc = [&](size_t bytes) { char* p = ws + off; off = (off + bytes + 255) & ~(size_t)255; return p; };
  int*            deg    = (int*)alloc((size_t)n * 4);
  float*          dinv   = (float*)alloc((size_t)n * 4);
  int*            excl   = (int*)alloc((size_t)n * 4);
  int*            blksum = (int*)alloc((size_t)nblk * 4);
  int*            rowptr = (int*)alloc((size_t)(n + 1) * 4);
  int*            rnk    = (int*)alloc((size_t)E * 4);
  int*            csr    = (int*)alloc((size_t)E * 4);
  unsigned short* w1t    = (unsigned short*)alloc(256 * 512 * 2);
  unsigned short* w2t    = (unsigned short*)alloc(64 * 256 * 2);
  unsigned short* hs1cb  = (unsigned short*)alloc((size_t)n * 256 * 2);  // [8][n][32]
  unsigned short* h1agg  = (unsigned short*)alloc((size_t)n * 256 * 2);  // [8][n][32]
  unsigned short* hs2b   = (unsigned short*)alloc((size_t)n * 64 * 2);
  unsigned short* xb     = (unsigned short*)alloc((size_t)n * 512 * 2);  // bf16 copy of x
  (void)ws_size; (void)n_in; (void)out_size;

  hipMemsetAsync(deg, 0, (size_t)n * 4, stream);
  k_deg<<<(E + 255) / 256, 256, 0, stream>>>(ei, deg, E, rnk, W1, W2, w1t, w2t);
  k_scanA<<<nblk, 256, 0, stream>>>(deg, excl, blksum, dinv, n);
  k_scanC<<<nblk, 256, 0, stream>>>(excl, blksum, rowptr, n, E);
  // atomic-free fill (rank trick) + xb conversion fused
  k_fillx<<<(NNODES * 512 / 8 + 255) / 256, 256, 0, stream>>>(ei, rowptr, rnk, csr, E, x, xb);
  // 49 groups x 32 blocks: row = (bid>>5)*8 + (bid&7), col = (bid>>3)&3
  k_gemm1<<<49 * 32, 256, 0, stream>>>(xb, w1t, dinv, hs1cb);
  // 8 slab-passes x 3125 dst-chunks (16 dsts each); pass = bid&7 -> XCD pinned
  k_agg1<<<3125 * 8, 256, 0, stream>>>(rowptr, csr, hs1cb, dinv, b1, h1agg);
  k_gemm2<<<(n + 63) / 64, 256, 0, stream>>>(h1agg, w2t, dinv, hs2b);
  k_agg2f<<<(n + 3) / 4, 256, 0, stream>>>(rowptr, csr, hs2b, dinv, b2, out);
}

// Round 12
// 211.628 us; speedup vs baseline: 1.2853x; 1.2853x over previous
//
#include <hip/hip_runtime.h>
#include <hip/hip_bf16.h>

typedef __attribute__((ext_vector_type(8))) short short8;
typedef __attribute__((ext_vector_type(4))) float f32x4;

#define NNODES 50000

__device__ __forceinline__ float b2f(unsigned short s) {
  union { unsigned int u; float f; } c; c.u = ((unsigned int)s) << 16;
  return c.f;
}
__device__ __forceinline__ unsigned short f2b(float f) {
  return __bfloat16_as_ushort(__float2bfloat16(f));  // RNE
}
__device__ __forceinline__ unsigned int pkcvt(float a, float b) {
  return (unsigned int)f2b(a) | ((unsigned int)f2b(b) << 16);
}

// global_load_lds, 16B per lane: per-lane GLOBAL src addr, wave-uniform LDS
// base; HW writes LDS at base + lane*16 (m104 semantics).
__device__ __forceinline__ void gl_lds16(const void* g, void* l) {
  __builtin_amdgcn_global_load_lds((const __attribute__((address_space(1))) unsigned int*)g,
                                   (__attribute__((address_space(3))) unsigned int*)l, 16, 0, 0);
}

// ---------------- degree histogram (+rank) + W transpose/bf16 + x->bf16 ----------------
// Conversion placed HERE (R2-R5's proven placement): the histogram is atomic-
// latency-bound at low BW, the conversion is pure streaming -- fused they run
// at ~max instead of sum. Grid sized for the conversion (12500 blocks).
__global__ __launch_bounds__(256) void k_deg(const int* __restrict__ ei, int* __restrict__ deg, int E,
                                             int* __restrict__ rnk,
                                             const float* __restrict__ W1, const float* __restrict__ W2,
                                             unsigned short* __restrict__ w1t, unsigned short* __restrict__ w2t,
                                             const float* __restrict__ x, unsigned short* __restrict__ xb) {
  int idx = blockIdx.x * 256 + threadIdx.x;
  if (idx < E) {
    int r = atomicAdd(&deg[ei[E + idx]], 1);   // return value IS the edge's rank
    rnk[idx] = r;
  }
  if (idx < 256 * 512) { int nn = idx >> 9, kk = idx & 511; w1t[idx] = f2b(W1[kk * 256 + nn]); }
  int i2 = idx - 256 * 512;
  if (i2 >= 0 && i2 < 64 * 256) { int nn = i2 >> 8, kk = i2 & 255; w2t[i2] = f2b(W2[kk * 64 + nn]); }
  if (idx < (NNODES * 512) / 8) {
    const float4 v0 = *(const float4*)(x + (size_t)idx * 8);
    const float4 v1 = *(const float4*)(x + (size_t)idx * 8 + 4);
    uint4 p;
    p.x = pkcvt(v0.x, v0.y); p.y = pkcvt(v0.z, v0.w);
    p.z = pkcvt(v1.x, v1.y); p.w = pkcvt(v1.z, v1.w);
    *(uint4*)(xb + (size_t)idx * 8) = p;
  }
}

// ---------------- scan phase A ----------------
__global__ __launch_bounds__(256) void k_scanA(const int* __restrict__ deg, int* __restrict__ excl,
                                               int* __restrict__ blksum, float* __restrict__ dinv, int n) {
  const int i = blockIdx.x * 256 + threadIdx.x;
  const int lane = threadIdx.x & 63, wid = threadIdx.x >> 6;
  const int v = (i < n) ? deg[i] : 0;
  int x = v;
#pragma unroll
  for (int o = 1; o < 64; o <<= 1) {
    int y = __shfl_up(x, o, 64);
    if (lane >= o) x += y;
  }
  __shared__ int wsum[4];
  if (lane == 63) wsum[wid] = x;
  __syncthreads();
  int woff = 0;
  for (int w = 0; w < wid; ++w) woff += wsum[w];
  const int incl = x + woff;
  if (i < n) {
    excl[i] = incl - v;
    dinv[i] = rsqrtf((float)v + 1.0f);  // +1 self loop
  }
  if (threadIdx.x == 255) blksum[blockIdx.x] = incl;
}

// ---------------- scan phase C ----------------
__global__ __launch_bounds__(256) void k_scanC(const int* __restrict__ excl, const int* __restrict__ blksum,
                                               int* __restrict__ rowptr, int n, int E) {
  const int t = threadIdx.x;
  int partial = 0;
  for (int j = t; j < (int)blockIdx.x; j += 256) partial += blksum[j];
#pragma unroll
  for (int o = 32; o > 0; o >>= 1) partial += __shfl_xor(partial, o, 64);
  __shared__ int ws[4];
  if ((t & 63) == 0) ws[t >> 6] = partial;
  __syncthreads();
  const int off = ws[0] + ws[1] + ws[2] + ws[3];
  const int i = blockIdx.x * 256 + t;
  if (i < n) rowptr[i] = excl[i] + off;
  if (i == 0) rowptr[n] = E;
}

// ---------------- atomic-free CSR fill (rank trick) ----------------
// pos = rowptr[dst] + rank[e]: pipelined random 4B gather (rowptr, L2-hot)
// + fire-and-forget scatter. No RMW dependency chain.
__global__ __launch_bounds__(256) void k_fill(const int* __restrict__ ei, const int* __restrict__ rowptr,
                                              const int* __restrict__ rnk, int* __restrict__ csr, int E) {
  int idx = blockIdx.x * 256 + threadIdx.x;
  if (idx < E) {
    const int dst = ei[E + idx];
    csr[rowptr[dst] + rnk[idx]] = ei[idx];
  }
}

// ---------------- GEMM1: hs1b = bf16(dinv[row] * (xb @ W1)) ----------------
// R7 config (128x64, the measured local optimum; 128x128 regressed +6us in
// R8 -- at these small K-panels TLP beats per-wave work amplification).
// Depth-2 pipelined gl_lds staging, counted vmcnt(3), both-sides chunk-XOR
// swizzle. LDS 24KB -> 6 blocks/CU; grid 1568 ~ 6.1/CU all-resident.
__global__ __launch_bounds__(256) void k_gemm1(const unsigned short* __restrict__ xb,
    const unsigned short* __restrict__ w1t, const float* __restrict__ dinv,
    unsigned short* __restrict__ hs1b) {
  const int M = NNODES, K = 512, N = 256;
  const int NRB = (NNODES + 127) / 128;  // 391
  const int bid = blockIdx.x;
  const int rowblk = (bid >> 5) * 8 + (bid & 7);
  const int colblk = (bid >> 3) & 3;
  if (rowblk >= NRB) return;

  __shared__ unsigned short Ab[2][128][32];  // 16 KB
  __shared__ unsigned short Bb[2][64][32];   //  8 KB

  const int tid = threadIdx.x;
  const int w = tid >> 6, lane = tid & 63;
  const int sub = lane >> 2;                 // staging row within wave window
  const int brow = rowblk * 128, bcol = colblk * 64;
  const int wr = w >> 1, wc = w & 1;         // 2x2 wave grid, 64x32 out each
  const int lr = lane & 15, lk = lane >> 4;

  const int swc = ((lane & 3) ^ ((lane >> 3) & 3)) * 8;   // pre-swizzled src chunk
  const int rch = (lk ^ ((lr >> 1) & 3)) * 8;             // read-side swizzled chunk

  int gr0 = brow + w * 16 + sub;      if (gr0 >= M) gr0 = M - 1;
  int gr1 = brow + 64 + w * 16 + sub; if (gr1 >= M) gr1 = M - 1;
  const int grB = bcol + w * 16 + sub;

  const unsigned short* a0p = xb + (size_t)gr0 * K + swc;
  const unsigned short* a1p = xb + (size_t)gr1 * K + swc;
  const unsigned short* bp  = w1t + (size_t)grB * K + swc;

  f32x4 acc[4][2] = {};

#define G1_STAGE(BUF, KT) do { \
    gl_lds16(a0p + (KT), &Ab[BUF][w * 16][0]); \
    gl_lds16(a1p + (KT), &Ab[BUF][64 + w * 16][0]); \
    gl_lds16(bp  + (KT), &Bb[BUF][w * 16][0]); \
  } while (0)

  G1_STAGE(0, 0);
  G1_STAGE(1, 32);
  asm volatile("s_waitcnt vmcnt(3)" ::: "memory");  // stage 0 done; stage 1 in flight
  __builtin_amdgcn_s_barrier();

  for (int s = 0; s < 16; ++s) {
    const int cur = s & 1;
    short8 af[4], bf[2];
#pragma unroll
    for (int m = 0; m < 4; ++m) af[m] = *(const short8*)&Ab[cur][wr * 64 + m * 16 + lr][rch];
#pragma unroll
    for (int n = 0; n < 2; ++n) bf[n] = *(const short8*)&Bb[cur][wc * 32 + n * 16 + lr][rch];
    if (s < 14) {
      asm volatile("s_waitcnt lgkmcnt(0)" ::: "memory");  // frags in regs
      __builtin_amdgcn_s_barrier();                       // all waves done with buf cur
      G1_STAGE(cur, (s + 2) * 32);                        // tile s+2 -> buf cur
    }
#pragma unroll
    for (int m = 0; m < 4; ++m)
#pragma unroll
      for (int n = 0; n < 2; ++n)
        acc[m][n] = __builtin_amdgcn_mfma_f32_16x16x32_bf16(af[m], bf[n], acc[m][n], 0, 0, 0);
    if (s < 14)      asm volatile("s_waitcnt vmcnt(3)" ::: "memory");  // s+1 landed; s+2 in flight
    else if (s == 14) asm volatile("s_waitcnt vmcnt(0)" ::: "memory"); // last stage (tile 15) landed
    if (s < 15) __builtin_amdgcn_s_barrier();
  }
#undef G1_STAGE

#pragma unroll
  for (int m = 0; m < 4; ++m) {
#pragma unroll
    for (int n = 0; n < 2; ++n) {
      const int col = bcol + wc * 32 + n * 16 + lr;
#pragma unroll
      for (int j = 0; j < 4; ++j) {
        const int row = brow + wr * 64 + m * 16 + lk * 4 + j;
        if (row < M) hs1b[(size_t)row * N + col] = f2b(acc[m][n][j] * dinv[row]);
      }
    }
  }
}

// ---------------- FUSED agg1 + relu/bias + GEMM2 + prescale -> hs2b ----------------
// R2's proven 8-deep gather batch (16-deep measured WORSE: 79 vs 72 us).
// 16 nodes/block, wave gathers 4 nodes; phase 2: wave w computes cols
// w*16..w*16+15 of the 16x64 output. At its measured replication floor:
// 185MB fetch @ ~2.7TB/s (full-row pull gather, per-XCD L2 replication);
// slab-sharding alternatives (R3/R10/R11) all land at 71-73us effective.
__global__ __launch_bounds__(256) void k_agg1g(const int* __restrict__ rowptr,
    const int* __restrict__ csr, const unsigned short* __restrict__ hs1b,
    const float* __restrict__ dinv, const float* __restrict__ b1,
    const unsigned short* __restrict__ w2t, unsigned short* __restrict__ hs2b) {
  const int M = NNODES;
  __shared__ unsigned short h1t[16][264];  // 8.4 KB
  const int tid = threadIdx.x;
  const int w = tid >> 6, lane = tid & 63;
  const int lr = lane & 15, lk = lane >> 4;
  const int brow = blockIdx.x * 16;

  const float4 bb = *(const float4*)(b1 + lane * 4);

  // ---- phase 1: each wave aggregates 4 nodes ----
  for (int i = 0; i < 4; ++i) {
    const int ldsrow = w * 4 + i;
    const int d = brow + ldsrow;
    f32x4 acc = {0.f, 0.f, 0.f, 0.f};
    if (d < M) {
      const int a = rowptr[d], bnd = rowptr[d + 1];
      ushort4 sv = *(const ushort4*)(hs1b + (size_t)d * 256 + lane * 4);  // self loop
      acc[0] = b2f(sv.x); acc[1] = b2f(sv.y); acc[2] = b2f(sv.z); acc[3] = b2f(sv.w);
      int e = a;
      for (; e + 8 <= bnd; e += 8) {
        int s[8];
#pragma unroll
        for (int j = 0; j < 8; ++j) s[j] = csr[e + j];
        ushort4 v[8];
#pragma unroll
        for (int j = 0; j < 8; ++j) v[j] = *(const ushort4*)(hs1b + (size_t)s[j] * 256 + lane * 4);
#pragma unroll
        for (int j = 0; j < 8; ++j) {
          acc[0] += b2f(v[j].x); acc[1] += b2f(v[j].y);
          acc[2] += b2f(v[j].z); acc[3] += b2f(v[j].w);
        }
      }
      for (; e + 2 <= bnd; e += 2) {
        int s0 = csr[e], s1 = csr[e + 1];
        ushort4 v0 = *(const ushort4*)(hs1b + (size_t)s0 * 256 + lane * 4);
        ushort4 v1 = *(const ushort4*)(hs1b + (size_t)s1 * 256 + lane * 4);
        acc[0] += b2f(v0.x) + b2f(v1.x); acc[1] += b2f(v0.y) + b2f(v1.y);
        acc[2] += b2f(v0.z) + b2f(v1.z); acc[3] += b2f(v0.w) + b2f(v1.w);
      }
      for (; e < bnd; ++e) {
        int s0 = csr[e];
        ushort4 v0 = *(const ushort4*)(hs1b + (size_t)s0 * 256 + lane * 4);
        acc[0] += b2f(v0.x); acc[1] += b2f(v0.y); acc[2] += b2f(v0.z); acc[3] += b2f(v0.w);
      }
      const float di = dinv[d];
      acc[0] = fmaxf(0.f, acc[0] * di + bb.x);
      acc[1] = fmaxf(0.f, acc[1] * di + bb.y);
      acc[2] = fmaxf(0.f, acc[2] * di + bb.z);
      acc[3] = fmaxf(0.f, acc[3] * di + bb.w);
    }
    uint2 pk;
    pk.x = pkcvt(acc[0], acc[1]);
    pk.y = pkcvt(acc[2], acc[3]);
    *(uint2*)&h1t[ldsrow][lane * 4] = pk;
  }

  __syncthreads();

  // ---- phase 2: 16x64x256 MFMA; wave w -> cols w*16..w*16+15 ----
  f32x4 acc2 = {};
#pragma unroll
  for (int s = 0; s < 8; ++s) {
    short8 af = *(const short8*)&h1t[lr][s * 32 + lk * 8];
    short8 bfv = *(const short8*)(w2t + (size_t)(w * 16 + lr) * 256 + s * 32 + lk * 8);
    acc2 = __builtin_amdgcn_mfma_f32_16x16x32_bf16(af, bfv, acc2, 0, 0, 0);
  }

  {
    const int col = w * 16 + lr;
#pragma unroll
    for (int j = 0; j < 4; ++j) {
      const int row = brow + lk * 4 + j;
      if (row < M) hs2b[(size_t)row * 64 + col] = f2b(acc2[j] * dinv[row]);
    }
  }
}

// ---------------- fused agg2 + bias + log_softmax: wave per dst node (R7 version) ----------------
__global__ __launch_bounds__(256) void k_agg2f(const int* __restrict__ rowptr,
    const int* __restrict__ csr, const unsigned short* __restrict__ hs2b,
    const float* __restrict__ dinv, const float* __restrict__ b2,
    float* __restrict__ out) {
  const int d = blockIdx.x * 4 + (threadIdx.x >> 6);
  if (d >= NNODES) return;
  const int lane = threadIdx.x & 63;
  const int a = rowptr[d], bnd = rowptr[d + 1];

  float acc = b2f(hs2b[(size_t)d * 64 + lane]);

  int i = a;
  for (; i + 16 <= bnd; i += 16) {
    int s[16];
#pragma unroll
    for (int j = 0; j < 16; ++j) s[j] = csr[i + j];
    unsigned short v[16];
#pragma unroll
    for (int j = 0; j < 16; ++j) v[j] = hs2b[(size_t)s[j] * 64 + lane];
#pragma unroll
    for (int j = 0; j < 16; ++j) acc += b2f(v[j]);
  }
  for (; i + 4 <= bnd; i += 4) {
    int s[4];
#pragma unroll
    for (int j = 0; j < 4; ++j) s[j] = csr[i + j];
    unsigned short v[4];
#pragma unroll
    for (int j = 0; j < 4; ++j) v[j] = hs2b[(size_t)s[j] * 64 + lane];
#pragma unroll
    for (int j = 0; j < 4; ++j) acc += b2f(v[j]);
  }
  for (; i < bnd; ++i) acc += b2f(hs2b[(size_t)csr[i] * 64 + lane]);

  float v = acc * dinv[d] + b2[lane];
  float m = v;
#pragma unroll
  for (int o = 32; o > 0; o >>= 1) m = fmaxf(m, __shfl_xor(m, o, 64));
  float ex = expf(v - m);
  float s = ex;
#pragma unroll
  for (int o = 32; o > 0; o >>= 1) s += __shfl_xor(s, o, 64);
  out[(size_t)d * 64 + lane] = v - m - logf(s);
}

extern "C" void kernel_launch(void* const* d_in, const int* in_sizes, int n_in,
                              void* d_out, int out_size, void* d_ws, size_t ws_size,
                              hipStream_t stream) {
  const float* x  = (const float*)d_in[0];
  const int*   ei = (const int*)d_in[1];
  const float* W1 = (const float*)d_in[2];
  const float* b1 = (const float*)d_in[3];
  const float* W2 = (const float*)d_in[4];
  const float* b2 = (const float*)d_in[5];
  float* out = (float*)d_out;
  const int E = in_sizes[1] / 2;
  const int n = NNODES;
  const int nblk = (n + 255) / 256;

  char* ws = (char*)d_ws;
  size_t off = 0;
  auto alloc = [&](size_t bytes) { char* p = ws + off; off = (off + bytes + 255) & ~(size_t)255; return p; };
  int*            deg    = (int*)alloc((size_t)n * 4);
  float*          dinv   = (float*)alloc((size_t)n * 4);
  int*            excl   = (int*)alloc((size_t)n * 4);
  int*            blksum = (int*)alloc((size_t)nblk * 4);
  int*            rowptr = (int*)alloc((size_t)(n + 1) * 4);
  int*            rnk    = (int*)alloc((size_t)E * 4);
  int*            csr    = (int*)alloc((size_t)E * 4);
  unsigned short* w1t    = (unsigned short*)alloc(256 * 512 * 2);
  unsigned short* w2t    = (unsigned short*)alloc(64 * 256 * 2);
  unsigned short* hs1b   = (unsigned short*)alloc((size_t)n * 256 * 2);
  unsigned short* hs2b   = (unsigned short*)alloc((size_t)n * 64 * 2);
  unsigned short* xb     = (unsigned short*)alloc((size_t)n * 512 * 2);  // bf16 copy of x
  (void)ws_size; (void)n_in; (void)out_size;

  hipMemsetAsync(deg, 0, (size_t)n * 4, stream);
  // histogram+rank + W cvts + xb conversion fused (overlap atomics with streaming)
  k_deg<<<(NNODES * 512 / 8 + 255) / 256, 256, 0, stream>>>(ei, deg, E, rnk, W1, W2, w1t, w2t, x, xb);
  k_scanA<<<nblk, 256, 0, stream>>>(deg, excl, blksum, dinv, n);
  k_scanC<<<nblk, 256, 0, stream>>>(excl, blksum, rowptr, n, E);
  // atomic-free fill (rank trick), lean
  k_fill<<<(E + 255) / 256, 256, 0, stream>>>(ei, rowptr, rnk, csr, E);
  // 49 groups x 32 blocks: row = (bid>>5)*8 + (bid&7), col = (bid>>3)&3
  k_gemm1<<<49 * 32, 256, 0, stream>>>(xb, w1t, dinv, hs1b);
  k_agg1g<<<(n + 15) / 16, 256, 0, stream>>>(rowptr, csr, hs1b, dinv, b1, w2t, hs2b);
  k_agg2f<<<(n + 3) / 4, 256, 0, stream>>>(rowptr, csr, hs2b, dinv, b2, out);
}